// Round 5
// baseline (306.572 us; speedup 1.0000x reference)
//
#include <hip/hip_runtime.h>
#include <math.h>

#define N_   8
#define CIN  512
#define MID  256
#define OUTC 256
#define H_   56
#define W_   56
#define HW   3136
#define EPS  1e-5f

typedef __attribute__((ext_vector_type(8))) short short8;
typedef __attribute__((ext_vector_type(4))) float floatx4;
typedef __attribute__((ext_vector_type(2))) float floatx2;

__device__ __forceinline__ float bf2f(unsigned short b) {
  unsigned int u = ((unsigned int)b) << 16;
  return __builtin_bit_cast(float, u);
}
__device__ __forceinline__ unsigned short f2bf(float f) {
  unsigned int u = __builtin_bit_cast(unsigned int, f);
  unsigned int r = u + 0x7fffu + ((u >> 16) & 1u);
  return (unsigned short)(r >> 16);
}
__device__ __forceinline__ unsigned int pack2bf(float f0, float f1) {
  unsigned int u0 = __builtin_bit_cast(unsigned int, f0);
  unsigned int u1 = __builtin_bit_cast(unsigned int, f1);
  u0 += 0x7fffu + ((u0 >> 16) & 1u);
  u1 += 0x7fffu + ((u1 >> 16) & 1u);
  return (u0 >> 16) | (u1 & 0xffff0000u);
}
// unpack a dword of 2 bf16 -> (low, high) as packed floats
__device__ __forceinline__ floatx2 up2(unsigned int u) {
  floatx2 r;
  r.x = __builtin_bit_cast(float, u << 16);
  r.y = __builtin_bit_cast(float, u & 0xffff0000u);
  return r;
}

// workspace layout (bytes)
#define XF_BF_BYTES  (N_*HW*MID*2)        // 12,845,056
#define OFF_BYTES    (N_*HW*18*4)         //  1,806,336
#define WBF_BYTES    (256*2304*2)         //  1,179,648
#define WK2_BYTES    (2*72*64*8*2)        //    147,456
#define W1_BYTES     (64*256*8*2)         //    262,144
#define XB_BYTES     ((size_t)N_*HW*CIN*2)// 25,690,112

// ---------------- prep: dcn_w [O][C][9] -> wbf bf16 [r/8][o][j] (r = tap*256+c) ----
__global__ __launch_bounds__(256) void prep_wbf(const float* __restrict__ dcn_w,
                                                unsigned short* __restrict__ wbf) {
  int e = blockIdx.x * 256 + threadIdx.x;
  int rb  = e >> 11;
  int rem = e & 2047;
  int o   = rem >> 3;
  int j   = e & 7;
  int r   = rb * 8 + j;
  int tap = r >> 8;
  int c   = r & 255;
  wbf[e] = f2bf(dcn_w[(o * 256 + c) * 9 + tap]);
}

// ---------------- prep: off_w -> wk2 A-frag layout (M pad 18->32) ----------------
__global__ __launch_bounds__(256) void prep_wk2(const float* __restrict__ off_w,
                                                unsigned short* __restrict__ wk2) {
  int e = blockIdx.x * 256 + threadIdx.x;
  int j  = e & 7;
  int l  = (e >> 3) & 63;
  int q  = e >> 9;
  int ot = (q >= 72) ? 1 : 0;
  int ks = q - ot * 72;
  int o  = ot * 16 + (l & 15);
  int r  = ks * 32 + ((l >> 4) << 3) + j;
  int tap = r >> 8;
  int c   = r & 255;
  float v = (o < 18) ? off_w[(o * 256 + c) * 9 + tap] : 0.f;
  wk2[e] = f2bf(v);
}

// ---------------- prep: conv1_w [256][512] -> w1bf A-frag [c/8][m][8] ----------------
__global__ __launch_bounds__(256) void prep_w1(const float* __restrict__ conv1_w,
                                               unsigned short* __restrict__ w1bf) {
  int e = blockIdx.x * 256 + threadIdx.x;
  int rb = e >> 11;
  int m  = (e >> 3) & 255;
  int j  = e & 7;
  int c  = rb * 8 + j;
  w1bf[e] = f2bf(conv1_w[m * 512 + c]);
}

// ---------------- prep: x NCHW fp32 -> xb NHWC bf16 ----------------
#define TP 72
__global__ __launch_bounds__(256) void prep_x(const float* __restrict__ x,
                                              unsigned short* __restrict__ xb) {
  __shared__ unsigned short T[32 * TP];
  const int t  = threadIdx.x;
  const int n  = blockIdx.z;
  const int c0 = blockIdx.y * 32;
  const int p0 = blockIdx.x * 64;

  {
    int c = t >> 3, pg = t & 7;
    const float4* src = (const float4*)(x + ((size_t)(n * CIN + c0 + c)) * HW + p0 + pg * 8);
    float4 v0 = src[0];
    float4 v1 = src[1];
    unsigned int d0 = pack2bf(v0.x, v0.y), d1 = pack2bf(v0.z, v0.w);
    unsigned int d2 = pack2bf(v1.x, v1.y), d3 = pack2bf(v1.z, v1.w);
    uint2 a; a.x = d0; a.y = d1;
    uint2 b; b.x = d2; b.y = d3;
    *(uint2*)&T[c * TP + pg * 8]     = a;
    *(uint2*)&T[c * TP + pg * 8 + 4] = b;
  }
  __syncthreads();
  {
    int p = t >> 2, cq = t & 3;
    unsigned short o8[8];
    #pragma unroll
    for (int j = 0; j < 8; ++j) o8[j] = T[(cq * 8 + j) * TP + p];
    *(short8*)(xb + ((size_t)(n * HW) + p0 + p) * CIN + c0 + cq * 8) = *(short8*)o8;
  }
}

// ---------------- K1: conv1 MFMA GEMM + BN1 + upsample + attention -> xf ----------------
#define K1SP 520
#define XSP  264

__global__ __launch_bounds__(256) void k1_gemm(
    const unsigned short* __restrict__ xb,
    const unsigned short* __restrict__ w1bf,
    const float* __restrict__ y,
    const float* __restrict__ g1, const float* __restrict__ b1,
    const float* __restrict__ m1, const float* __restrict__ v1,
    const float* __restrict__ att_w, const float* __restrict__ att_b,
    float* __restrict__ xf_out,
    unsigned short* __restrict__ xf_bf) {
  __shared__ unsigned short S[32 * K1SP];
  __shared__ float part[2][32][17];
  __shared__ float zz[2][32];

  const int t    = threadIdx.x;
  const int n    = blockIdx.x / 98;
  const int pix0 = (blockIdx.x % 98) * 32;

  {
    const int p = t >> 3, cg = t & 7;
    const short8* src = (const short8*)(xb + ((size_t)(n * HW) + pix0 + p) * CIN) + cg * 8;
    short8* dst = (short8*)&S[p * K1SP + cg * 64];
    #pragma unroll
    for (int j = 0; j < 8; ++j) dst[j] = src[j];
  }
  __syncthreads();

  const int w  = t >> 6;
  const int l  = t & 63;
  const int lo = l & 15;
  const int hi = l >> 4;

  floatx4 acc[4][2];
  #pragma unroll
  for (int i = 0; i < 4; ++i)
    #pragma unroll
    for (int j = 0; j < 2; ++j)
      acc[i][j] = (floatx4){0.f, 0.f, 0.f, 0.f};

  const short8* wbase = (const short8*)w1bf;

  #pragma unroll 4
  for (int ks = 0; ks < 16; ++ks) {
    int rb = ks * 4 + hi;
    const short8* wp = wbase + ((rb << 8) + (w << 6) + lo);
    short8 wa0 = wp[0];
    short8 wa1 = wp[16];
    short8 wa2 = wp[32];
    short8 wa3 = wp[48];
    const unsigned short* sp = &S[lo * K1SP + (ks << 5) + (hi << 3)];
    short8 sb0 = *(const short8*)sp;
    short8 sb1 = *(const short8*)(sp + 16 * K1SP);
    acc[0][0] = __builtin_amdgcn_mfma_f32_16x16x32_bf16(wa0, sb0, acc[0][0], 0, 0, 0);
    acc[0][1] = __builtin_amdgcn_mfma_f32_16x16x32_bf16(wa0, sb1, acc[0][1], 0, 0, 0);
    acc[1][0] = __builtin_amdgcn_mfma_f32_16x16x32_bf16(wa1, sb0, acc[1][0], 0, 0, 0);
    acc[1][1] = __builtin_amdgcn_mfma_f32_16x16x32_bf16(wa1, sb1, acc[1][1], 0, 0, 0);
    acc[2][0] = __builtin_amdgcn_mfma_f32_16x16x32_bf16(wa2, sb0, acc[2][0], 0, 0, 0);
    acc[2][1] = __builtin_amdgcn_mfma_f32_16x16x32_bf16(wa2, sb1, acc[2][1], 0, 0, 0);
    acc[3][0] = __builtin_amdgcn_mfma_f32_16x16x32_bf16(wa3, sb0, acc[3][0], 0, 0, 0);
    acc[3][1] = __builtin_amdgcn_mfma_f32_16x16x32_bf16(wa3, sb1, acc[3][1], 0, 0, 0);
  }

  const int pixA = pix0 + lo, pixB = pixA + 16;
  const int hA = pixA / 56, wxA = pixA - hA * 56;
  const int hB = pixB / 56, wxB = pixB - hB * 56;
  const int yoA = (hA >> 1) * 28 + (wxA >> 1);
  const int yoB = (hB >> 1) * 28 + (wxB >> 1);
  const float* yb = y + (size_t)n * MID * 784;

  float xmv[4][2][4];
  float s0A = 0.f, s0B = 0.f, s1A = 0.f, s1B = 0.f;
  #pragma unroll
  for (int i = 0; i < 4; ++i) {
    #pragma unroll
    for (int r = 0; r < 4; ++r) {
      int o = (w << 6) + (i << 4) + (hi << 2) + r;
      float sc = g1[o] * rsqrtf(v1[o] + EPS);
      float sh = fmaf(-m1[o], sc, b1[o]);
      float xA = fmaf(acc[i][0][r], sc, sh);
      float xB = fmaf(acc[i][1][r], sc, sh);
      xmv[i][0][r] = xA; xmv[i][1][r] = xB;
      float yA = yb[o * 784 + yoA];
      float yB = yb[o * 784 + yoB];
      float a0x = att_w[o], a0y = att_w[256 + o];
      float a1x = att_w[512 + o], a1y = att_w[768 + o];
      s0A = fmaf(a0x, xA, fmaf(a0y, yA, s0A));
      s0B = fmaf(a0x, xB, fmaf(a0y, yB, s0B));
      s1A = fmaf(a1x, xA, fmaf(a1y, yA, s1A));
      s1B = fmaf(a1x, xB, fmaf(a1y, yB, s1B));
    }
  }
  {
    int slot = (w << 2) + hi;
    part[0][lo][slot]      = s0A;
    part[0][16 + lo][slot] = s0B;
    part[1][lo][slot]      = s1A;
    part[1][16 + lo][slot] = s1B;
  }
  __syncthreads();
  if (t < 64) {
    int a = t >> 5, pp = t & 31;
    float s = att_b[a];
    #pragma unroll
    for (int g = 0; g < 16; ++g) s += part[a][pp][g];
    zz[a][pp] = 1.f / (1.f + expf(-s));
  }
  __syncthreads();

  {
    unsigned short* Sx = S;
    float z0A = zz[0][lo], z0B = zz[0][16 + lo];
    float z1A = zz[1][lo], z1B = zz[1][16 + lo];
    #pragma unroll
    for (int i = 0; i < 4; ++i) {
      #pragma unroll
      for (int r = 0; r < 4; ++r) {
        int o = (w << 6) + (i << 4) + (hi << 2) + r;
        float yA = yb[o * 784 + yoA];
        float yB = yb[o * 784 + yoB];
        float xfA = fmaf(xmv[i][0][r], z0A, yA * z1A);
        float xfB = fmaf(xmv[i][1][r], z0B, yB * z1B);
        float* ob = xf_out + (size_t)(n * MID + o) * HW;
        ob[pixA] = xfA;
        ob[pixB] = xfB;
        Sx[lo * XSP + o]        = f2bf(xfA);
        Sx[(16 + lo) * XSP + o] = f2bf(xfB);
      }
    }
  }
  __syncthreads();
  {
    const unsigned short* Sx = S;
    const int p = t >> 3, cg = t & 7;
    unsigned short* dst = xf_bf + ((size_t)(n * HW) + pix0 + p) * MID + cg * 32;
    #pragma unroll
    for (int j = 0; j < 4; ++j)
      *(short8*)(dst + j * 8) = *(const short8*)&Sx[p * XSP + cg * 32 + j * 8];
  }
}

// ---------------- K2: 3x3 conv -> 18 offset channels, bf16 MFMA (16-pix tiles) ----
#define K2P  16
#define K2SP 264

__global__ __launch_bounds__(256) void k2_offconv_mfma(
    const unsigned short* __restrict__ xf_bf,
    const unsigned short* __restrict__ wk2,
    float* __restrict__ off_out) {
  __shared__ unsigned short S[K2P * K2SP];   // 8,448 B
  __shared__ float red2[4][K2P][19];         // 4,864 B

  const int t    = threadIdx.x;
  const int n    = blockIdx.x / 196;
  const int pix0 = (blockIdx.x % 196) * K2P;

  const int l  = t & 63;
  const int lo = l & 15;
  const int hi = l >> 4;
  const int w  = t >> 6;     // K-quarter

  floatx4 acc0 = {0.f, 0.f, 0.f, 0.f};
  floatx4 acc1 = {0.f, 0.f, 0.f, 0.f};

  // staging role: thread -> (pixel p, 16-channel chunk cg)
  const int p   = t >> 4;
  const int cg  = t & 15;
  const int pix = pix0 + p;
  const int hh  = pix / 56;
  const int ww  = pix - hh * 56;

  const short8* wb8 = (const short8*)wk2;

  for (int tap = 0; tap < 9; ++tap) {
    const int ky = tap / 3, kx = tap - (tap / 3) * 3;
    const int yy = hh - 1 + ky, xx = ww - 1 + kx;
    const bool valid = ((unsigned)yy < 56u) && ((unsigned)xx < 56u);
    const int src = ((n * HW) + yy * 56 + xx) << 8;

    __syncthreads();
    {
      const int c0 = cg * 16;
      short8 v0 = (short8){0,0,0,0,0,0,0,0};
      short8 v1 = v0;
      if (valid) {
        v0 = *(const short8*)(xf_bf + src + c0);
        v1 = *(const short8*)(xf_bf + src + c0 + 8);
      }
      *(short8*)&S[p * K2SP + c0]     = v0;
      *(short8*)&S[p * K2SP + c0 + 8] = v1;
    }
    __syncthreads();

    #pragma unroll
    for (int s = 0; s < 2; ++s) {
      const int kst = (w << 1) + s;        // K32-step within tap (0..7)
      const int ks  = tap * 8 + kst;
      short8 bfrag = *(const short8*)&S[lo * K2SP + kst * 32 + hi * 8];
      short8 a0 = wb8[(0 * 72 + ks) * 64 + l];
      short8 a1 = wb8[(1 * 72 + ks) * 64 + l];
      acc0 = __builtin_amdgcn_mfma_f32_16x16x32_bf16(a0, bfrag, acc0, 0, 0, 0);
      acc1 = __builtin_amdgcn_mfma_f32_16x16x32_bf16(a1, bfrag, acc1, 0, 0, 0);
    }
  }

  #pragma unroll
  for (int r = 0; r < 4; ++r) {
    int row = hi * 4 + r;
    red2[w][lo][row] = acc0[r];
    int o1 = 16 + row;
    if (o1 < 18) red2[w][lo][o1] = acc1[r];
  }
  __syncthreads();
  for (int e = t; e < K2P * 18; e += 256) {
    int pp = e / 18, oo = e - pp * 18;
    float sres = red2[0][pp][oo] + red2[1][pp][oo] + red2[2][pp][oo] + red2[3][pp][oo];
    off_out[((size_t)(n * HW) + pix0) * 18 + e] = sres;
  }
}

// ---------------- K3: deformable conv + BN2, bf16 MFMA (16-pix tiles) ----------------
#define PB3 16
#define SP3 264

__global__ __launch_bounds__(256) void k3_deform_mfma(
    const unsigned short* __restrict__ xf_bf, const float* __restrict__ off_in,
    const unsigned short* __restrict__ wbf,
    const float* __restrict__ g2, const float* __restrict__ b2,
    const float* __restrict__ m2, const float* __restrict__ v2,
    float* __restrict__ out) {
  __shared__ unsigned short S[PB3 * SP3];   // 8,448 B
  __shared__ float cw[144][4];              // 2,304 B
  __shared__ int   ad[144][4];              // 2,304 B
  __shared__ float offs[PB3 * 18];          // 1,152 B

  const int t    = threadIdx.x;
  const int n    = blockIdx.x / 196;
  const int pix0 = (blockIdx.x % 196) * PB3;

  for (int e = t; e < PB3 * 18; e += 256)
    offs[e] = off_in[((size_t)(n * HW) + pix0) * 18 + e];
  __syncthreads();

  if (t < 144) {
    int p = t / 9, k = t - p * 9;
    int ky = k / 3, kx = k - ky * 3;
    int pix = pix0 + p;
    int hh = pix / 56, ww = pix - hh * 56;
    float sy = (float)(hh - 1 + ky) + offs[p * 18 + 2 * k];
    float sx = (float)(ww - 1 + kx) + offs[p * 18 + 2 * k + 1];
    float y0f = floorf(sy), x0f = floorf(sx);
    int y0 = (int)y0f, x0 = (int)x0f;
    float wy = sy - y0f, wx = sx - x0f;
    float w00 = (1.f - wy) * (1.f - wx), w01 = (1.f - wy) * wx;
    float w10 = wy * (1.f - wx),         w11 = wy * wx;
    bool yv0 = (unsigned)y0 < 56u, yv1 = (unsigned)(y0 + 1) < 56u;
    bool xv0 = (unsigned)x0 < 56u, xv1 = (unsigned)(x0 + 1) < 56u;
    int base = n * HW;
    ad[t][0] = (yv0 && xv0) ? (base + y0 * 56 + x0) * 256         : 0;
    ad[t][1] = (yv0 && xv1) ? (base + y0 * 56 + x0 + 1) * 256     : 0;
    ad[t][2] = (yv1 && xv0) ? (base + (y0+1) * 56 + x0) * 256     : 0;
    ad[t][3] = (yv1 && xv1) ? (base + (y0+1) * 56 + x0 + 1) * 256 : 0;
    cw[t][0] = (yv0 && xv0) ? w00 : 0.f;
    cw[t][1] = (yv0 && xv1) ? w01 : 0.f;
    cw[t][2] = (yv1 && xv0) ? w10 : 0.f;
    cw[t][3] = (yv1 && xv1) ? w11 : 0.f;
  }

  const int w  = t >> 6;
  const int l  = t & 63;
  const int lo = l & 15;
  const int hi = l >> 4;

  floatx4 acc[4];
  #pragma unroll
  for (int i = 0; i < 4; ++i) acc[i] = (floatx4){0.f, 0.f, 0.f, 0.f};

  const short8* wbase = (const short8*)wbf;

  // staging role: thread -> (pixel p, 16-channel chunk cg)
  const int sp_p  = t >> 4;
  const int sp_cg = t & 15;

  for (int tap = 0; tap < 9; ++tap) {
    __syncthreads();
    {
      const int s = sp_p * 9 + tap;
      const int a0 = ad[s][0], a1 = ad[s][1], a2 = ad[s][2], a3 = ad[s][3];
      const float w0 = cw[s][0], w1 = cw[s][1], w2 = cw[s][2], w3 = cw[s][3];
      #pragma unroll
      for (int g = 0; g < 2; ++g) {
        const int c0 = sp_cg * 16 + g * 8;
        uint4 ua = *(const uint4*)(xf_bf + a0 + c0);
        uint4 ub = *(const uint4*)(xf_bf + a1 + c0);
        uint4 uc = *(const uint4*)(xf_bf + a2 + c0);
        uint4 ud = *(const uint4*)(xf_bf + a3 + c0);
        unsigned int pk[4];
        const unsigned int* pa = (const unsigned int*)&ua;
        const unsigned int* pb = (const unsigned int*)&ub;
        const unsigned int* pc = (const unsigned int*)&uc;
        const unsigned int* pd = (const unsigned int*)&ud;
        #pragma unroll
        for (int u = 0; u < 4; ++u) {
          floatx2 fa = up2(pa[u]), fb = up2(pb[u]);
          floatx2 fc = up2(pc[u]), fd = up2(pd[u]);
          floatx2 rr = fa * w0 + fb * w1 + fc * w2 + fd * w3;
          pk[u] = pack2bf(rr.x, rr.y);
        }
        uint4 ov; ov.x = pk[0]; ov.y = pk[1]; ov.z = pk[2]; ov.w = pk[3];
        *(uint4*)&S[sp_p * SP3 + c0] = ov;
      }
    }
    __syncthreads();

    #pragma unroll
    for (int ks = 0; ks < 8; ++ks) {
      int rb = tap * 32 + ks * 4 + hi;
      const short8* wp = wbase + ((rb << 8) + (w << 6) + lo);
      short8 wa0 = wp[0];
      short8 wa1 = wp[16];
      short8 wa2 = wp[32];
      short8 wa3 = wp[48];
      short8 sb = *(const short8*)&S[lo * SP3 + (ks << 5) + (hi << 3)];
      acc[0] = __builtin_amdgcn_mfma_f32_16x16x32_bf16(wa0, sb, acc[0], 0, 0, 0);
      acc[1] = __builtin_amdgcn_mfma_f32_16x16x32_bf16(wa1, sb, acc[1], 0, 0, 0);
      acc[2] = __builtin_amdgcn_mfma_f32_16x16x32_bf16(wa2, sb, acc[2], 0, 0, 0);
      acc[3] = __builtin_amdgcn_mfma_f32_16x16x32_bf16(wa3, sb, acc[3], 0, 0, 0);
    }
  }

  #pragma unroll
  for (int i = 0; i < 4; ++i) {
    #pragma unroll
    for (int r = 0; r < 4; ++r) {
      int o = (w << 6) + (i << 4) + (hi << 2) + r;
      float scv = g2[o] * rsqrtf(v2[o] + EPS);
      float shv = b2[o] - m2[o] * scv;
      out[((size_t)(n * OUTC + o)) * HW + pix0 + lo] = fmaf(acc[i][r], scv, shv);
    }
  }
}

extern "C" void kernel_launch(void* const* d_in, const int* in_sizes, int n_in,
                              void* d_out, int out_size, void* d_ws, size_t ws_size,
                              hipStream_t stream) {
  const float* x       = (const float*)d_in[0];
  const float* y       = (const float*)d_in[1];
  const float* conv1_w = (const float*)d_in[2];
  const float* g1      = (const float*)d_in[3];
  const float* b1      = (const float*)d_in[4];
  const float* m1      = (const float*)d_in[5];
  const float* v1      = (const float*)d_in[6];
  const float* att_w   = (const float*)d_in[7];
  const float* att_b   = (const float*)d_in[8];
  const float* off_w   = (const float*)d_in[9];
  const float* dcn_w   = (const float*)d_in[10];
  const float* g2      = (const float*)d_in[11];
  const float* b2      = (const float*)d_in[12];
  const float* m2      = (const float*)d_in[13];
  const float* v2      = (const float*)d_in[14];

  float* out    = (float*)d_out;
  float* xf_out = out + (size_t)N_ * OUTC * HW;

  char* ws = (char*)d_ws;
  unsigned short* xf_bf   = (unsigned short*)ws;
  float*          off_buf = (float*)(ws + XF_BF_BYTES);
  unsigned short* wbf     = (unsigned short*)(ws + XF_BF_BYTES + OFF_BYTES);
  unsigned short* wk2     = (unsigned short*)(ws + XF_BF_BYTES + OFF_BYTES + WBF_BYTES);
  unsigned short* w1bf    = (unsigned short*)(ws + XF_BF_BYTES + OFF_BYTES + WBF_BYTES + WK2_BYTES);
  unsigned short* xb      = (unsigned short*)(ws + XF_BF_BYTES + OFF_BYTES + WBF_BYTES + WK2_BYTES + W1_BYTES);

  hipLaunchKernelGGL(prep_wbf, dim3(2304), dim3(256), 0, stream, dcn_w, wbf);
  hipLaunchKernelGGL(prep_wk2, dim3(288), dim3(256), 0, stream, off_w, wk2);
  hipLaunchKernelGGL(prep_w1, dim3(512), dim3(256), 0, stream, conv1_w, w1bf);
  hipLaunchKernelGGL(prep_x, dim3(49, 16, N_), dim3(256), 0, stream, x, xb);
  hipLaunchKernelGGL(k1_gemm, dim3(784), dim3(256), 0, stream,
                     xb, w1bf, y, g1, b1, m1, v1, att_w, att_b, xf_out, xf_bf);
  hipLaunchKernelGGL(k2_offconv_mfma, dim3(1568), dim3(256), 0, stream,
                     xf_bf, wk2, off_buf);
  hipLaunchKernelGGL(k3_deform_mfma, dim3(1568), dim3(256), 0, stream,
                     xf_bf, off_buf, wbf, g2, b2, m2, v2, out);
}

// Round 6
// 271.528 us; speedup vs baseline: 1.1291x; 1.1291x over previous
//
#include <hip/hip_runtime.h>
#include <math.h>

#define N_   8
#define CIN  512
#define MID  256
#define OUTC 256
#define H_   56
#define W_   56
#define HW   3136
#define EPS  1e-5f

typedef __attribute__((ext_vector_type(8))) short short8;
typedef __attribute__((ext_vector_type(4))) float floatx4;
typedef __attribute__((ext_vector_type(2))) float floatx2;

__device__ __forceinline__ float bf2f(unsigned short b) {
  unsigned int u = ((unsigned int)b) << 16;
  return __builtin_bit_cast(float, u);
}
__device__ __forceinline__ unsigned short f2bf(float f) {
  unsigned int u = __builtin_bit_cast(unsigned int, f);
  unsigned int r = u + 0x7fffu + ((u >> 16) & 1u);
  return (unsigned short)(r >> 16);
}
__device__ __forceinline__ unsigned int pack2bf(float f0, float f1) {
  unsigned int u0 = __builtin_bit_cast(unsigned int, f0);
  unsigned int u1 = __builtin_bit_cast(unsigned int, f1);
  u0 += 0x7fffu + ((u0 >> 16) & 1u);
  u1 += 0x7fffu + ((u1 >> 16) & 1u);
  return (u0 >> 16) | (u1 & 0xffff0000u);
}
__device__ __forceinline__ floatx2 up2(unsigned int u) {
  floatx2 r;
  r.x = __builtin_bit_cast(float, u << 16);
  r.y = __builtin_bit_cast(float, u & 0xffff0000u);
  return r;
}

// workspace layout (bytes)
#define XF_BF_BYTES  (N_*HW*MID*2)
#define OFF_BYTES    (N_*HW*18*4)
#define WBF_BYTES    (256*2304*2)
#define WK2_BYTES    (2*72*64*8*2)
#define W1_BYTES     (64*256*8*2)

// ---------------- prep: dcn_w [O][C][9] -> wbf bf16 [r/8][o][j] (r = tap*256+c) ----
__global__ __launch_bounds__(256) void prep_wbf(const float* __restrict__ dcn_w,
                                                unsigned short* __restrict__ wbf) {
  int e = blockIdx.x * 256 + threadIdx.x;
  int rb  = e >> 11;
  int rem = e & 2047;
  int o   = rem >> 3;
  int j   = e & 7;
  int r   = rb * 8 + j;
  int tap = r >> 8;
  int c   = r & 255;
  wbf[e] = f2bf(dcn_w[(o * 256 + c) * 9 + tap]);
}

// ---------------- prep: off_w -> wk2 A-frag layout (M pad 18->32) ----------------
__global__ __launch_bounds__(256) void prep_wk2(const float* __restrict__ off_w,
                                                unsigned short* __restrict__ wk2) {
  int e = blockIdx.x * 256 + threadIdx.x;
  int j  = e & 7;
  int l  = (e >> 3) & 63;
  int q  = e >> 9;
  int ot = (q >= 72) ? 1 : 0;
  int ks = q - ot * 72;
  int o  = ot * 16 + (l & 15);
  int r  = ks * 32 + ((l >> 4) << 3) + j;
  int tap = r >> 8;
  int c   = r & 255;
  float v = (o < 18) ? off_w[(o * 256 + c) * 9 + tap] : 0.f;
  wk2[e] = f2bf(v);
}

// ---------------- prep: conv1_w [256][512] -> w1bf A-frag [c/8][m][8] ----------------
__global__ __launch_bounds__(256) void prep_w1(const float* __restrict__ conv1_w,
                                               unsigned short* __restrict__ w1bf) {
  int e = blockIdx.x * 256 + threadIdx.x;
  int rb = e >> 11;
  int m  = (e >> 3) & 255;
  int j  = e & 7;
  int c  = rb * 8 + j;
  w1bf[e] = f2bf(conv1_w[m * 512 + c]);
}

// ---------------- prep: x NCHW fp32 -> xb NHWC bf16 ----------------
#define TP 72
__global__ __launch_bounds__(256) void prep_x(const float* __restrict__ x,
                                              unsigned short* __restrict__ xb) {
  __shared__ unsigned short T[32 * TP];
  const int t  = threadIdx.x;
  const int n  = blockIdx.z;
  const int c0 = blockIdx.y * 32;
  const int p0 = blockIdx.x * 64;

  {
    int c = t >> 3, pg = t & 7;
    const float4* src = (const float4*)(x + ((size_t)(n * CIN + c0 + c)) * HW + p0 + pg * 8);
    float4 v0 = src[0];
    float4 v1 = src[1];
    unsigned int d0 = pack2bf(v0.x, v0.y), d1 = pack2bf(v0.z, v0.w);
    unsigned int d2 = pack2bf(v1.x, v1.y), d3 = pack2bf(v1.z, v1.w);
    uint2 a; a.x = d0; a.y = d1;
    uint2 b; b.x = d2; b.y = d3;
    *(uint2*)&T[c * TP + pg * 8]     = a;
    *(uint2*)&T[c * TP + pg * 8 + 4] = b;
  }
  __syncthreads();
  {
    int p = t >> 2, cq = t & 3;
    unsigned short o8[8];
    #pragma unroll
    for (int j = 0; j < 8; ++j) o8[j] = T[(cq * 8 + j) * TP + p];
    *(short8*)(xb + ((size_t)(n * HW) + p0 + p) * CIN + c0 + cq * 8) = *(short8*)o8;
  }
}

// ---------------- K1: conv1 MFMA GEMM + BN1 + upsample + attention -> xf ----------------
#define K1SP 520
#define XSP  264

__global__ __launch_bounds__(256) void k1_gemm(
    const unsigned short* __restrict__ xb,
    const unsigned short* __restrict__ w1bf,
    const float* __restrict__ y,
    const float* __restrict__ g1, const float* __restrict__ b1,
    const float* __restrict__ m1, const float* __restrict__ v1,
    const float* __restrict__ att_w, const float* __restrict__ att_b,
    float* __restrict__ xf_out,
    unsigned short* __restrict__ xf_bf) {
  __shared__ unsigned short S[32 * K1SP];
  __shared__ float part[2][32][17];
  __shared__ float zz[2][32];

  const int t    = threadIdx.x;
  const int n    = blockIdx.x & 7;
  const int pix0 = (blockIdx.x >> 3) * 32;

  {
    const int p = t >> 3, cg = t & 7;
    const short8* src = (const short8*)(xb + ((size_t)(n * HW) + pix0 + p) * CIN) + cg * 8;
    short8* dst = (short8*)&S[p * K1SP + cg * 64];
    #pragma unroll
    for (int j = 0; j < 8; ++j) dst[j] = src[j];
  }
  __syncthreads();

  const int w  = t >> 6;
  const int l  = t & 63;
  const int lo = l & 15;
  const int hi = l >> 4;

  floatx4 acc[4][2];
  #pragma unroll
  for (int i = 0; i < 4; ++i)
    #pragma unroll
    for (int j = 0; j < 2; ++j)
      acc[i][j] = (floatx4){0.f, 0.f, 0.f, 0.f};

  const short8* wbase = (const short8*)w1bf;

  #pragma unroll 4
  for (int ks = 0; ks < 16; ++ks) {
    int rb = ks * 4 + hi;
    const short8* wp = wbase + ((rb << 8) + (w << 6) + lo);
    short8 wa0 = wp[0];
    short8 wa1 = wp[16];
    short8 wa2 = wp[32];
    short8 wa3 = wp[48];
    const unsigned short* sp = &S[lo * K1SP + (ks << 5) + (hi << 3)];
    short8 sb0 = *(const short8*)sp;
    short8 sb1 = *(const short8*)(sp + 16 * K1SP);
    acc[0][0] = __builtin_amdgcn_mfma_f32_16x16x32_bf16(wa0, sb0, acc[0][0], 0, 0, 0);
    acc[0][1] = __builtin_amdgcn_mfma_f32_16x16x32_bf16(wa0, sb1, acc[0][1], 0, 0, 0);
    acc[1][0] = __builtin_amdgcn_mfma_f32_16x16x32_bf16(wa1, sb0, acc[1][0], 0, 0, 0);
    acc[1][1] = __builtin_amdgcn_mfma_f32_16x16x32_bf16(wa1, sb1, acc[1][1], 0, 0, 0);
    acc[2][0] = __builtin_amdgcn_mfma_f32_16x16x32_bf16(wa2, sb0, acc[2][0], 0, 0, 0);
    acc[2][1] = __builtin_amdgcn_mfma_f32_16x16x32_bf16(wa2, sb1, acc[2][1], 0, 0, 0);
    acc[3][0] = __builtin_amdgcn_mfma_f32_16x16x32_bf16(wa3, sb0, acc[3][0], 0, 0, 0);
    acc[3][1] = __builtin_amdgcn_mfma_f32_16x16x32_bf16(wa3, sb1, acc[3][1], 0, 0, 0);
  }

  const int pixA = pix0 + lo, pixB = pixA + 16;
  const int hA = pixA / 56, wxA = pixA - hA * 56;
  const int hB = pixB / 56, wxB = pixB - hB * 56;
  const int yoA = (hA >> 1) * 28 + (wxA >> 1);
  const int yoB = (hB >> 1) * 28 + (wxB >> 1);
  const float* yb = y + (size_t)n * MID * 784;

  float xmv[4][2][4];
  float s0A = 0.f, s0B = 0.f, s1A = 0.f, s1B = 0.f;
  #pragma unroll
  for (int i = 0; i < 4; ++i) {
    #pragma unroll
    for (int r = 0; r < 4; ++r) {
      int o = (w << 6) + (i << 4) + (hi << 2) + r;
      float sc = g1[o] * rsqrtf(v1[o] + EPS);
      float sh = fmaf(-m1[o], sc, b1[o]);
      float xA = fmaf(acc[i][0][r], sc, sh);
      float xB = fmaf(acc[i][1][r], sc, sh);
      xmv[i][0][r] = xA; xmv[i][1][r] = xB;
      float yA = yb[o * 784 + yoA];
      float yB = yb[o * 784 + yoB];
      float a0x = att_w[o], a0y = att_w[256 + o];
      float a1x = att_w[512 + o], a1y = att_w[768 + o];
      s0A = fmaf(a0x, xA, fmaf(a0y, yA, s0A));
      s0B = fmaf(a0x, xB, fmaf(a0y, yB, s0B));
      s1A = fmaf(a1x, xA, fmaf(a1y, yA, s1A));
      s1B = fmaf(a1x, xB, fmaf(a1y, yB, s1B));
    }
  }
  {
    int slot = (w << 2) + hi;
    part[0][lo][slot]      = s0A;
    part[0][16 + lo][slot] = s0B;
    part[1][lo][slot]      = s1A;
    part[1][16 + lo][slot] = s1B;
  }
  __syncthreads();
  if (t < 64) {
    int a = t >> 5, pp = t & 31;
    float s = att_b[a];
    #pragma unroll
    for (int g = 0; g < 16; ++g) s += part[a][pp][g];
    zz[a][pp] = 1.f / (1.f + expf(-s));
  }
  __syncthreads();

  {
    unsigned short* Sx = S;
    float z0A = zz[0][lo], z0B = zz[0][16 + lo];
    float z1A = zz[1][lo], z1B = zz[1][16 + lo];
    #pragma unroll
    for (int i = 0; i < 4; ++i) {
      #pragma unroll
      for (int r = 0; r < 4; ++r) {
        int o = (w << 6) + (i << 4) + (hi << 2) + r;
        float yA = yb[o * 784 + yoA];
        float yB = yb[o * 784 + yoB];
        float xfA = fmaf(xmv[i][0][r], z0A, yA * z1A);
        float xfB = fmaf(xmv[i][1][r], z0B, yB * z1B);
        float* ob = xf_out + (size_t)(n * MID + o) * HW;
        ob[pixA] = xfA;
        ob[pixB] = xfB;
        Sx[lo * XSP + o]        = f2bf(xfA);
        Sx[(16 + lo) * XSP + o] = f2bf(xfB);
      }
    }
  }
  __syncthreads();
  {
    const unsigned short* Sx = S;
    const int p = t >> 3, cg = t & 7;
    unsigned short* dst = xf_bf + ((size_t)(n * HW) + pix0 + p) * MID + cg * 32;
    #pragma unroll
    for (int j = 0; j < 4; ++j)
      *(short8*)(dst + j * 8) = *(const short8*)&Sx[p * XSP + cg * 32 + j * 8];
  }
}

// ---------------- K2: 3x3 conv -> 18 offset channels, bf16 MFMA (16-pix tiles) ----
#define K2P  16
#define K2SP 264

__global__ __launch_bounds__(256) void k2_offconv_mfma(
    const unsigned short* __restrict__ xf_bf,
    const unsigned short* __restrict__ wk2,
    float* __restrict__ off_out) {
  __shared__ unsigned short S[K2P * K2SP];
  __shared__ float red2[4][K2P][19];

  const int t    = threadIdx.x;
  const int n    = blockIdx.x & 7;
  const int pix0 = (blockIdx.x >> 3) * K2P;

  const int l  = t & 63;
  const int lo = l & 15;
  const int hi = l >> 4;
  const int w  = t >> 6;

  floatx4 acc0 = {0.f, 0.f, 0.f, 0.f};
  floatx4 acc1 = {0.f, 0.f, 0.f, 0.f};

  const int p   = t >> 4;
  const int cg  = t & 15;
  const int pix = pix0 + p;
  const int hh  = pix / 56;
  const int ww  = pix - hh * 56;

  const short8* wb8 = (const short8*)wk2;

  for (int tap = 0; tap < 9; ++tap) {
    const int ky = tap / 3, kx = tap - (tap / 3) * 3;
    const int yy = hh - 1 + ky, xx = ww - 1 + kx;
    const bool valid = ((unsigned)yy < 56u) && ((unsigned)xx < 56u);
    const int src = ((n * HW) + yy * 56 + xx) << 8;

    __syncthreads();
    {
      const int c0 = cg * 16;
      short8 v0 = (short8){0,0,0,0,0,0,0,0};
      short8 v1 = v0;
      if (valid) {
        v0 = *(const short8*)(xf_bf + src + c0);
        v1 = *(const short8*)(xf_bf + src + c0 + 8);
      }
      *(short8*)&S[p * K2SP + c0]     = v0;
      *(short8*)&S[p * K2SP + c0 + 8] = v1;
    }
    __syncthreads();

    #pragma unroll
    for (int s = 0; s < 2; ++s) {
      const int kst = (w << 1) + s;
      const int ks  = tap * 8 + kst;
      short8 bfrag = *(const short8*)&S[lo * K2SP + kst * 32 + hi * 8];
      short8 a0 = wb8[(0 * 72 + ks) * 64 + l];
      short8 a1 = wb8[(1 * 72 + ks) * 64 + l];
      acc0 = __builtin_amdgcn_mfma_f32_16x16x32_bf16(a0, bfrag, acc0, 0, 0, 0);
      acc1 = __builtin_amdgcn_mfma_f32_16x16x32_bf16(a1, bfrag, acc1, 0, 0, 0);
    }
  }

  #pragma unroll
  for (int r = 0; r < 4; ++r) {
    int row = hi * 4 + r;
    red2[w][lo][row] = acc0[r];
    int o1 = 16 + row;
    if (o1 < 18) red2[w][lo][o1] = acc1[r];
  }
  __syncthreads();
  for (int e = t; e < K2P * 18; e += 256) {
    int pp = e / 18, oo = e - pp * 18;
    float sres = red2[0][pp][oo] + red2[1][pp][oo] + red2[2][pp][oo] + red2[3][pp][oo];
    off_out[((size_t)(n * HW) + pix0) * 18 + e] = sres;
  }
}

// ---------------- K3: deformable conv + BN2, bf16 MFMA, 32-pix, dbuf pipeline ----
#define PB 32
#define SPITCH 264

__global__ __launch_bounds__(256, 3) void k3_deform_mfma(
    const unsigned short* __restrict__ xf_bf, const float* __restrict__ off_in,
    const unsigned short* __restrict__ wbf,
    const float* __restrict__ g2, const float* __restrict__ b2,
    const float* __restrict__ m2, const float* __restrict__ v2,
    float* __restrict__ out) {
  __shared__ unsigned short S[2][PB * SPITCH];  // 2 x 16,896 B
  __shared__ float cw[288][4];                  // 4,608 B
  __shared__ int   ad[288][4];                  // 4,608 B
  __shared__ float offs[PB * 18];               // 2,304 B

  const int t    = threadIdx.x;
  const int n    = blockIdx.x & 7;              // XCD-pinned image
  const int pix0 = (blockIdx.x >> 3) * PB;

  for (int e = t; e < PB * 18; e += 256)
    offs[e] = off_in[((size_t)(n * HW) + pix0) * 18 + e];
  __syncthreads();

  for (int e = t; e < 288; e += 256) {
    int p = e / 9, k = e - p * 9;
    int ky = k / 3, kx = k - ky * 3;
    int pix = pix0 + p;
    int hh = pix / 56, ww = pix - hh * 56;
    float sy = (float)(hh - 1 + ky) + offs[p * 18 + 2 * k];
    float sx = (float)(ww - 1 + kx) + offs[p * 18 + 2 * k + 1];
    float y0f = floorf(sy), x0f = floorf(sx);
    int y0 = (int)y0f, x0 = (int)x0f;
    float wy = sy - y0f, wx = sx - x0f;
    float w00 = (1.f - wy) * (1.f - wx), w01 = (1.f - wy) * wx;
    float w10 = wy * (1.f - wx),         w11 = wy * wx;
    bool yv0 = (unsigned)y0 < 56u, yv1 = (unsigned)(y0 + 1) < 56u;
    bool xv0 = (unsigned)x0 < 56u, xv1 = (unsigned)(x0 + 1) < 56u;
    int base = n * HW;
    ad[e][0] = (yv0 && xv0) ? (base + y0 * 56 + x0) * 256         : 0;
    ad[e][1] = (yv0 && xv1) ? (base + y0 * 56 + x0 + 1) * 256     : 0;
    ad[e][2] = (yv1 && xv0) ? (base + (y0+1) * 56 + x0) * 256     : 0;
    ad[e][3] = (yv1 && xv1) ? (base + (y0+1) * 56 + x0 + 1) * 256 : 0;
    cw[e][0] = (yv0 && xv0) ? w00 : 0.f;
    cw[e][1] = (yv0 && xv1) ? w01 : 0.f;
    cw[e][2] = (yv1 && xv0) ? w10 : 0.f;
    cw[e][3] = (yv1 && xv1) ? w11 : 0.f;
  }
  __syncthreads();   // tables ready for all threads

  const int w  = t >> 6;
  const int l  = t & 63;
  const int lo = l & 15;
  const int hi = l >> 4;

  floatx4 acc[4][2];
  #pragma unroll
  for (int i = 0; i < 4; ++i)
    #pragma unroll
    for (int j = 0; j < 2; ++j)
      acc[i][j] = (floatx4){0.f, 0.f, 0.f, 0.f};

  const short8* wbase = (const short8*)wbf;

  const int sp_p  = t >> 3;     // pixel 0..31
  const int sp_cg = t & 7;      // 8-ch group base

  uint4 ld[4][4];   // [corner][g] prefetch registers

  // gather corners for `tap` into ld
  #define GATHER(tap_, dst_)                                            \
    {                                                                   \
      const int s_ = sp_p * 9 + (tap_);                                 \
      const int a0_ = ad[s_][0], a1_ = ad[s_][1];                       \
      const int a2_ = ad[s_][2], a3_ = ad[s_][3];                       \
      _Pragma("unroll")                                                 \
      for (int g_ = 0; g_ < 4; ++g_) {                                  \
        const int c0_ = g_ * 64 + sp_cg * 8;                            \
        dst_[0][g_] = *(const uint4*)(xf_bf + a0_ + c0_);               \
        dst_[1][g_] = *(const uint4*)(xf_bf + a1_ + c0_);               \
        dst_[2][g_] = *(const uint4*)(xf_bf + a2_ + c0_);               \
        dst_[3][g_] = *(const uint4*)(xf_bf + a3_ + c0_);               \
      }                                                                 \
    }

  // blend ld and store into buffer buf_
  #define BLEND(tap_, src_, buf_)                                       \
    {                                                                   \
      const int s_ = sp_p * 9 + (tap_);                                 \
      const float w0_ = cw[s_][0], w1_ = cw[s_][1];                     \
      const float w2_ = cw[s_][2], w3_ = cw[s_][3];                     \
      _Pragma("unroll")                                                 \
      for (int g_ = 0; g_ < 4; ++g_) {                                  \
        const int c0_ = g_ * 64 + sp_cg * 8;                            \
        unsigned int pk_[4];                                            \
        const unsigned int* pa_ = (const unsigned int*)&src_[0][g_];    \
        const unsigned int* pb_ = (const unsigned int*)&src_[1][g_];    \
        const unsigned int* pc_ = (const unsigned int*)&src_[2][g_];    \
        const unsigned int* pd_ = (const unsigned int*)&src_[3][g_];    \
        _Pragma("unroll")                                               \
        for (int u_ = 0; u_ < 4; ++u_) {                                \
          floatx2 fa_ = up2(pa_[u_]), fb_ = up2(pb_[u_]);               \
          floatx2 fc_ = up2(pc_[u_]), fd_ = up2(pd_[u_]);               \
          floatx2 rr_ = fa_ * w0_ + fb_ * w1_ + fc_ * w2_ + fd_ * w3_;  \
          pk_[u_] = pack2bf(rr_.x, rr_.y);                              \
        }                                                               \
        uint4 ov_; ov_.x = pk_[0]; ov_.y = pk_[1];                      \
        ov_.z = pk_[2]; ov_.w = pk_[3];                                 \
        *(uint4*)&S[buf_][sp_p * SPITCH + c0_] = ov_;                   \
      }                                                                 \
    }

  // prologue: stage tap 0
  GATHER(0, ld);
  BLEND(0, ld, 0);

  for (int tap = 0; tap < 9; ++tap) {
    uint4 ldn[4][4];
    if (tap < 8) GATHER(tap + 1, ldn);    // VMEM in flight across barrier
    __syncthreads();                      // S[tap&1] writes visible

    const unsigned short* Sb = S[tap & 1];
    #pragma unroll
    for (int ks = 0; ks < 8; ++ks) {
      int rb = tap * 32 + ks * 4 + hi;
      const short8* wp = wbase + ((rb << 8) + (w << 6) + lo);
      short8 wa0 = wp[0];
      short8 wa1 = wp[16];
      short8 wa2 = wp[32];
      short8 wa3 = wp[48];
      const unsigned short* sp = &Sb[lo * SPITCH + (ks << 5) + (hi << 3)];
      short8 sb0 = *(const short8*)sp;
      short8 sb1 = *(const short8*)(sp + 16 * SPITCH);
      acc[0][0] = __builtin_amdgcn_mfma_f32_16x16x32_bf16(wa0, sb0, acc[0][0], 0, 0, 0);
      acc[0][1] = __builtin_amdgcn_mfma_f32_16x16x32_bf16(wa0, sb1, acc[0][1], 0, 0, 0);
      acc[1][0] = __builtin_amdgcn_mfma_f32_16x16x32_bf16(wa1, sb0, acc[1][0], 0, 0, 0);
      acc[1][1] = __builtin_amdgcn_mfma_f32_16x16x32_bf16(wa1, sb1, acc[1][1], 0, 0, 0);
      acc[2][0] = __builtin_amdgcn_mfma_f32_16x16x32_bf16(wa2, sb0, acc[2][0], 0, 0, 0);
      acc[2][1] = __builtin_amdgcn_mfma_f32_16x16x32_bf16(wa2, sb1, acc[2][1], 0, 0, 0);
      acc[3][0] = __builtin_amdgcn_mfma_f32_16x16x32_bf16(wa3, sb0, acc[3][0], 0, 0, 0);
      acc[3][1] = __builtin_amdgcn_mfma_f32_16x16x32_bf16(wa3, sb1, acc[3][1], 0, 0, 0);
    }

    if (tap < 8) BLEND(tap + 1, ldn, (tap + 1) & 1);
  }

  #pragma unroll
  for (int i = 0; i < 4; ++i) {
    #pragma unroll
    for (int r = 0; r < 4; ++r) {
      int o = (w << 6) + (i << 4) + (hi << 2) + r;
      float scv = g2[o] * rsqrtf(v2[o] + EPS);
      float shv = b2[o] - m2[o] * scv;
      float* ob = out + ((size_t)(n * OUTC + o)) * HW + pix0;
      ob[lo]      = fmaf(acc[i][0][r], scv, shv);
      ob[16 + lo] = fmaf(acc[i][1][r], scv, shv);
    }
  }
  #undef GATHER
  #undef BLEND
}

extern "C" void kernel_launch(void* const* d_in, const int* in_sizes, int n_in,
                              void* d_out, int out_size, void* d_ws, size_t ws_size,
                              hipStream_t stream) {
  const float* x       = (const float*)d_in[0];
  const float* y       = (const float*)d_in[1];
  const float* conv1_w = (const float*)d_in[2];
  const float* g1      = (const float*)d_in[3];
  const float* b1      = (const float*)d_in[4];
  const float* m1      = (const float*)d_in[5];
  const float* v1      = (const float*)d_in[6];
  const float* att_w   = (const float*)d_in[7];
  const float* att_b   = (const float*)d_in[8];
  const float* off_w   = (const float*)d_in[9];
  const float* dcn_w   = (const float*)d_in[10];
  const float* g2      = (const float*)d_in[11];
  const float* b2      = (const float*)d_in[12];
  const float* m2      = (const float*)d_in[13];
  const float* v2      = (const float*)d_in[14];

  float* out    = (float*)d_out;
  float* xf_out = out + (size_t)N_ * OUTC * HW;

  char* ws = (char*)d_ws;
  unsigned short* xf_bf   = (unsigned short*)ws;
  float*          off_buf = (float*)(ws + XF_BF_BYTES);
  unsigned short* wbf     = (unsigned short*)(ws + XF_BF_BYTES + OFF_BYTES);
  unsigned short* wk2     = (unsigned short*)(ws + XF_BF_BYTES + OFF_BYTES + WBF_BYTES);
  unsigned short* w1bf    = (unsigned short*)(ws + XF_BF_BYTES + OFF_BYTES + WBF_BYTES + WK2_BYTES);
  unsigned short* xb      = (unsigned short*)(ws + XF_BF_BYTES + OFF_BYTES + WBF_BYTES + WK2_BYTES + W1_BYTES);

  hipLaunchKernelGGL(prep_wbf, dim3(2304), dim3(256), 0, stream, dcn_w, wbf);
  hipLaunchKernelGGL(prep_wk2, dim3(288), dim3(256), 0, stream, off_w, wk2);
  hipLaunchKernelGGL(prep_w1, dim3(512), dim3(256), 0, stream, conv1_w, w1bf);
  hipLaunchKernelGGL(prep_x, dim3(49, 16, N_), dim3(256), 0, stream, x, xb);
  hipLaunchKernelGGL(k1_gemm, dim3(784), dim3(256), 0, stream,
                     xb, w1bf, y, g1, b1, m1, v1, att_w, att_b, xf_out, xf_bf);
  hipLaunchKernelGGL(k2_offconv_mfma, dim3(1568), dim3(256), 0, stream,
                     xf_bf, wk2, off_buf);
  hipLaunchKernelGGL(k3_deform_mfma, dim3(784), dim3(256), 0, stream,
                     xf_bf, off_buf, wbf, g2, b2, m2, v2, out);
}